// Round 20
// baseline (237.698 us; speedup 1.0000x reference)
//
#include <hip/hip_runtime.h>
#include <hip/hip_bf16.h>

typedef __hip_bfloat16 bf16;
typedef __attribute__((ext_vector_type(8))) short short8;
typedef __attribute__((ext_vector_type(4))) float f32x4;

struct bf16x8 { bf16 v[8]; };
struct bf16x4 { bf16 v[4]; };

__device__ __forceinline__ void gload_lds16(const void* g, void* l) {
  __builtin_amdgcn_global_load_lds(
      (const __attribute__((address_space(1))) void*)g,
      (__attribute__((address_space(3))) void*)l, 16, 0, 0);
}

__device__ __forceinline__ float wave_sum(float x) {
#pragma unroll
  for (int o = 32; o > 0; o >>= 1) x += __shfl_xor(x, o, 64);
  return x;
}

// ---- fused prep: build T + cast wq/wk/wv/wo + x + pack bias ---------------
// (mphiW cast moved into stage-A's gemm_castA_k)
__global__ void prep_cast_k(const float* __restrict__ wq, const float* __restrict__ wk,
                            const float* __restrict__ wv, const float* __restrict__ wo,
                            const float* __restrict__ x,
                            const float* __restrict__ bq, const float* __restrict__ bk,
                            const float* __restrict__ bv,
                            const float* __restrict__ basis,
                            bf16* __restrict__ wqkv, bf16* __restrict__ wo_bf,
                            bf16* __restrict__ x_bf,
                            float* __restrict__ qkv_bias, bf16* __restrict__ T) {
  int b = blockIdx.x, tid = threadIdx.x;
  if (b < 8192) {  // build T[k][l][s]
    size_t i8 = (size_t)b * 256 + tid;  // 2M
    size_t i = i8 * 8;
    int s0 = (int)(i & 1023);
    int l = (int)((i >> 10) & 1023);
    int k = (int)(i >> 20);
    bf16x8 o;
#pragma unroll
    for (int j = 0; j < 8; j++) {
      int s = s0 + j;
      o.v[j] = (s <= l) ? __float2bfloat16(basis[(size_t)(l - s) * 16 + k])
                        : __float2bfloat16(0.f);
    }
    ((bf16x8*)T)[i8] = o;
    return;
  }
  const float* src; bf16* dst; int i;
  if (b < 10240) {
    int bb = b - 8192;
    src = (bb < 512) ? wq : (bb < 1024) ? wk : (bb < 1536) ? wv : wo;
    dst = (bb < 512) ? wqkv : (bb < 1024) ? (wqkv + 1048576)
         : (bb < 1536) ? (wqkv + 2097152) : wo_bf;
    i = (bb & 511) * 256 + tid;
  } else if (b < 10752) { src = x; dst = x_bf; i = (b - 10240) * 256 + tid; }
  else {
    int j = (b - 10752) * 256 + tid;
    if (j < 3072) {
      const float* s = (j < 1024) ? bq : (j < 2048) ? bk : bv;
      qkv_bias[j] = s[j & 1023];
    }
    return;
  }
  const float4* p = (const float4*)src + (size_t)i * 2;
  float4 a = p[0], c = p[1];
  bf16x8 o;
  o.v[0] = __float2bfloat16(a.x); o.v[1] = __float2bfloat16(a.y);
  o.v[2] = __float2bfloat16(a.z); o.v[3] = __float2bfloat16(a.w);
  o.v[4] = __float2bfloat16(c.x); o.v[5] = __float2bfloat16(c.y);
  o.v[6] = __float2bfloat16(c.z); o.v[7] = __float2bfloat16(c.w);
  ((bf16x8*)dst)[i] = o;
}

// ---- stage-A GEMM with fused A-side f32->bf16 cast (reg-staged) -----------
// C[k][o][s] = Mphi_k @ X^T. A = mphiW f32 [1024][16384], B = x_bf.
__launch_bounds__(256)
__global__ void gemm_castA_k(const float* __restrict__ A, const bf16* __restrict__ B,
                             bf16* __restrict__ C) {
  __shared__ bf16 As[128 * 64];
  __shared__ bf16 Bs[128 * 64];
  const int tid = threadIdx.x;
  const int lane = tid & 63;
  const int wid = tid >> 6;
  const int wr = wid >> 1, wc = wid & 1;
  const int cpx = gridDim.x >> 3;
  const int logical = (blockIdx.x & 7) * cpx + (blockIdx.x >> 3);
  const int bx = logical & 7, by = (logical >> 3) & 7, bz = logical >> 6;
  const int r0 = by * 128, c0 = bx * 128;
  const float* Ab = A + (size_t)bz * 1024;
  f32x4 acc[4][4] = {};
  const int srow = tid >> 3, scol = (tid & 7) << 3;

  for (int t = 0; t < 16; ++t) {
    __syncthreads();
    const int k0 = t << 6;
    // A: reg-staged load f32 + cast + ds_write
#pragma unroll
    for (int i = 0; i < 4; i++) {
      int row = i * 32 + srow;
      const float4* p = (const float4*)(Ab + (size_t)(r0 + row) * 16384 + k0 + scol);
      float4 a = p[0], c2 = p[1];
      bf16x8 o;
      o.v[0] = __float2bfloat16(a.x);  o.v[1] = __float2bfloat16(a.y);
      o.v[2] = __float2bfloat16(a.z);  o.v[3] = __float2bfloat16(a.w);
      o.v[4] = __float2bfloat16(c2.x); o.v[5] = __float2bfloat16(c2.y);
      o.v[6] = __float2bfloat16(c2.z); o.v[7] = __float2bfloat16(c2.w);
      *(bf16x8*)&As[(row << 6) + scol] = o;
    }
    // B: async global->LDS
#pragma unroll
    for (int i = 0; i < 4; i++) {
      int row = i * 32 + srow;
      gload_lds16(B + (size_t)(c0 + row) * 1024 + k0 + scol, &Bs[(row << 6) + scol]);
    }
    asm volatile("s_waitcnt vmcnt(0)" ::: "memory");
    __syncthreads();
#pragma unroll
    for (int ks = 0; ks < 2; ks++) {
      const int colo = ks * 32 + (lane >> 4) * 8;
      short8 af[4], bfr[4];
#pragma unroll
      for (int m = 0; m < 4; m++)
        af[m] = *(const short8*)&As[(wr * 64 + m * 16 + (lane & 15)) * 64 + colo];
#pragma unroll
      for (int n = 0; n < 4; n++)
        bfr[n] = *(const short8*)&Bs[(wc * 64 + n * 16 + (lane & 15)) * 64 + colo];
#pragma unroll
      for (int m = 0; m < 4; m++)
#pragma unroll
        for (int n = 0; n < 4; n++)
          acc[m][n] = __builtin_amdgcn_mfma_f32_16x16x32_bf16(af[m], bfr[n], acc[m][n], 0, 0, 0);
    }
  }

  const int rb = r0 + wr * 64 + ((lane >> 4) << 2);
  const int cb = c0 + wc * 64 + (lane & 15);
#pragma unroll
  for (int n = 0; n < 4; n++) {
    const int col = cb + n * 16;
#pragma unroll
    for (int m = 0; m < 4; m++) {
#pragma unroll
      for (int j = 0; j < 4; j++) {
        const int row = rb + m * 16 + j;
        C[(size_t)bz * 1048576 + (size_t)row * 1024 + col] = __float2bfloat16(acc[m][n][j]);
      }
    }
  }
}

// ---------------- MFMA GEMM, C = A @ B^T (+bias). 128x128 tile, BK=64 ------
// SK3=1: stage3 mode, bz in [0,6) = (khalf*3 + w).
template<int TRI, int OUTBF, int HASB, int DBUF, int SK3>
__global__ void gemm_bt(const bf16* __restrict__ A, long sAb, int lda,
                        const bf16* __restrict__ B, long sBb, int ldb,
                        void* __restrict__ Cv, void* __restrict__ Cv2, int nbz1,
                        long sCb, int ldc,
                        const float* __restrict__ bias, int sbias, int K) {
  constexpr int NB = DBUF ? 2 : 1;
  __shared__ bf16 As[NB][128 * 64];
  __shared__ bf16 Bs[NB][128 * 64];
  const int tid = threadIdx.x;
  const int lane = tid & 63;
  const int wid = tid >> 6;
  const int wr = wid >> 1, wc = wid & 1;
  const int cpx = gridDim.x >> 3;
  const int logical = (blockIdx.x & 7) * cpx + (blockIdx.x >> 3);
  const int bx = logical & 7, by = (logical >> 3) & 7, bz = logical >> 6;
  const int r0 = by * 128, c0 = bx * 128;
  const bf16* Ab;
  const bf16* Bb;
  if (SK3) {
    int w_ = bz % 3, kh_ = bz / 3;
    Ab = A + kh_ * 512;
    Bb = B + (size_t)w_ * sBb + kh_ * 512;
  } else {
    Ab = A + (size_t)bz * sAb;
    Bb = B + (size_t)bz * sBb;
  }
  f32x4 acc[4][4] = {};
  const int nt = (TRI ? min(K, r0 + 128) : K) >> 6;

  const int srow = tid >> 3, scol = (tid & 7) << 3;

#define STAGE(buf, t)                                                         \
  {                                                                           \
    const int k0_ = (t) << 6;                                                 \
    _Pragma("unroll")                                                         \
    for (int i = 0; i < 4; i++) {                                             \
      int row = i * 32 + srow;                                                \
      gload_lds16(Ab + (size_t)(r0 + row) * lda + k0_ + scol,                 \
                  &As[buf][(row << 6) + scol]);                               \
    }                                                                         \
    _Pragma("unroll")                                                         \
    for (int i = 0; i < 4; i++) {                                             \
      int row = i * 32 + srow;                                                \
      gload_lds16(Bb + (size_t)(c0 + row) * ldb + k0_ + scol,                 \
                  &Bs[buf][(row << 6) + scol]);                               \
    }                                                                         \
  }

  int cur = 0;
  if (DBUF) STAGE(0, 0)
  for (int t = 0; t < nt; ++t) {
    if (DBUF) {
      if (t + 1 < nt) {
        STAGE(cur ^ 1, t + 1)
        asm volatile("s_waitcnt vmcnt(8)" ::: "memory");
      } else {
        asm volatile("s_waitcnt vmcnt(0)" ::: "memory");
      }
      __syncthreads();
    } else {
      __syncthreads();
      STAGE(0, t)
      asm volatile("s_waitcnt vmcnt(0)" ::: "memory");
      __syncthreads();
    }
#pragma unroll
    for (int ks = 0; ks < 2; ks++) {
      const int colo = ks * 32 + (lane >> 4) * 8;
      short8 af[4], bfr[4];
#pragma unroll
      for (int m = 0; m < 4; m++)
        af[m] = *(const short8*)&As[cur][(wr * 64 + m * 16 + (lane & 15)) * 64 + colo];
#pragma unroll
      for (int n = 0; n < 4; n++)
        bfr[n] = *(const short8*)&Bs[cur][(wc * 64 + n * 16 + (lane & 15)) * 64 + colo];
#pragma unroll
      for (int m = 0; m < 4; m++)
#pragma unroll
        for (int n = 0; n < 4; n++)
          acc[m][n] = __builtin_amdgcn_mfma_f32_16x16x32_bf16(af[m], bfr[n], acc[m][n], 0, 0, 0);
    }
    if (DBUF) { __syncthreads(); cur ^= 1; }
  }
#undef STAGE

  void* Cb = (bz < nbz1) ? Cv : Cv2;
  const int bzl = (bz < nbz1) ? bz : bz - nbz1;
  const int rb = r0 + wr * 64 + ((lane >> 4) << 2);
  const int cb = c0 + wc * 64 + (lane & 15);
#pragma unroll
  for (int n = 0; n < 4; n++) {
    const int col = cb + n * 16;
    float bv = HASB ? bias[bz * sbias + col] : 0.f;
#pragma unroll
    for (int m = 0; m < 4; m++) {
#pragma unroll
      for (int j = 0; j < 4; j++) {
        const int row = rb + m * 16 + j;
        size_t off = (size_t)bzl * sCb + (size_t)row * ldc + col;
        float v = acc[m][n][j] + bv;
        if (OUTBF) ((bf16*)Cb)[off] = __float2bfloat16(v);
        else       ((float*)Cb)[off] = v;
      }
    }
  }
}

// ---------------- split-K x16 reduce (two regions) + bias + cast -----------
__global__ void reduce16_k(const float* __restrict__ pA, const float* __restrict__ pB,
                           const float* __restrict__ bias, bf16* __restrict__ out) {
  int i4 = blockIdx.x * 256 + threadIdx.x;  // 256K float4s
  float4 v = *((const float4*)bias + (i4 & 255));
#pragma unroll
  for (int j = 0; j < 8; j++) {
    float4 a = *((const float4*)pA + i4 + j * 262144);
    v.x += a.x; v.y += a.y; v.z += a.z; v.w += a.w;
  }
#pragma unroll
  for (int j = 0; j < 8; j++) {
    float4 a = *((const float4*)pB + i4 + j * 262144);
    v.x += a.x; v.y += a.y; v.z += a.z; v.w += a.w;
  }
  bf16x4 o;
  o.v[0] = __float2bfloat16(v.x); o.v[1] = __float2bfloat16(v.y);
  o.v[2] = __float2bfloat16(v.z); o.v[3] = __float2bfloat16(v.w);
  ((bf16x4*)out)[i4] = o;
}

// ---------------- split-K x4 reduce + bias, f32 out ----------------
__global__ void reduce4f_k(const float* __restrict__ p, const float* __restrict__ bias,
                           float* __restrict__ out) {
  int i4 = blockIdx.x * 256 + threadIdx.x;  // 256K float4s
  float4 v = *((const float4*)bias + (i4 & 255));
#pragma unroll
  for (int j = 0; j < 4; j++) {
    float4 a = *((const float4*)p + i4 + j * 262144);
    v.x += a.x; v.y += a.y; v.z += a.z; v.w += a.w;
  }
  ((float4*)out)[i4] = v;
}

// ---- per-(h,l): sum split-K halves + bias; l2norm k,v; sim; qsum; gate ----
__global__ void qkv_post_k(const float* __restrict__ qkv, const float* __restrict__ W,
                           const float* __restrict__ wgb, const float* __restrict__ scale,
                           const float* __restrict__ bias,
                           float* __restrict__ kn, float* __restrict__ vn,
                           float* __restrict__ sim, float* __restrict__ gz, float* __restrict__ qs) {
  __shared__ float Wl[64][65];
  int tid = threadIdx.x;
#pragma unroll
  for (int i = 0; i < 16; i++) {
    int c = i * 256 + tid;
    Wl[c >> 6][c & 63] = W[c];
  }
  __syncthreads();
  int lane = tid & 63;
  int gw = blockIdx.x * 4 + (tid >> 6);
  int h = gw >> 10, l = gw & 1023;
  const float* base = qkv + (size_t)l * 1024 + h * 64 + lane;
  float q = base[0] + base[3145728] + bias[h * 64 + lane];
  float k = base[1048576] + base[4194304] + bias[1024 + h * 64 + lane];
  float v = base[2097152] + base[5242880] + bias[2048 + h * 64 + lane];
  float knv = k * (1.f / fmaxf(sqrtf(wave_sum(k * k)), 1e-12f));
  float vnv = v * (1.f / fmaxf(sqrtf(wave_sum(v * v)), 1e-12f));
  float simv = wave_sum(q * knv);
  float qsv = wave_sum(q);
  float inner = 0.f;
#pragma unroll 8
  for (int n = 0; n < 64; n++)
    inner += Wl[lane][n] * __shfl(knv, n, 64);
  float gl = wave_sum(vnv * inner) * scale[h] + wgb[0];
  float yy = gl > 0.f ? gl : 0.01f * gl;
  float gzz = yy * yy + 1e-5f;
  size_t o = ((size_t)h * 1024 + l) * 64 + lane;
  kn[o] = knv; vn[o] = vnv;
  if (lane == 0) {
    sim[h * 1024 + l] = simv; gz[h * 1024 + l] = gzz; qs[h * 1024 + l] = qsv;
  }
}

// ---- fused: per-(c,h) local softmax-scan + gated outer-product state ------
__global__ void scan_outer_k(const float* __restrict__ sim, const float* __restrict__ gz,
                             const float* __restrict__ vn, const float* __restrict__ kn,
                             float* __restrict__ vloc, float* __restrict__ mloc,
                             float* __restrict__ nloc, float* __restrict__ gloc,
                             float* __restrict__ mA, float* __restrict__ nA,
                             float* __restrict__ vA, float* __restrict__ gA,
                             float* __restrict__ Mc) {
  __shared__ float vns[64][64], kns[64][64], gzs[64];
  int c = blockIdx.x, h = blockIdx.y, tid = threadIdx.x;
  size_t base = ((size_t)h * 1024 + c * 64) * 64;
#pragma unroll
  for (int i = 0; i < 16; i++) {
    int e = i * 256 + tid;
    vns[e >> 6][e & 63] = vn[base + e];
    kns[e >> 6][e & 63] = kn[base + e];
  }
  if (tid < 64) gzs[tid] = gz[h * 1024 + c * 64 + tid];
  __syncthreads();
  float acc[16] = {};
  for (int s = 0; s < 64; s++) {
    float g = gzs[s];
#pragma unroll
    for (int i = 0; i < 16; i++) {
      int pn = i * 256 + tid;
      acc[i] += (g * vns[s][pn >> 6]) * kns[s][pn & 63];
    }
  }
  size_t ob = (size_t)(h * 16 + c) * 4096;
#pragma unroll
  for (int i = 0; i < 16; i++) Mc[ob + i * 256 + tid] = acc[i];
  if (tid < 64) {
    int lane = tid;
    size_t hb = (size_t)h * 1024 + c * 64;
    float m = -1e30f, n = 0.f, v = 0.f, g = 0.f;
    for (int i = 0; i < 64; i++) {
      float s = sim[hb + i];
      float vv = vns[i][lane];
      float mn = fmaxf(m, s);
      float eo = expf(m - mn);
      float en = expf(s - mn);
      n = n * eo + en;
      v = v * eo + en * vv;
      m = mn;
      g += gzs[i];
      vloc[(hb + i) * 64 + lane] = v;
      if (lane == 0) { mloc[hb + i] = m; nloc[hb + i] = n; gloc[hb + i] = g; }
    }
    size_t ix = (size_t)h * 16 + c;
    vA[ix * 64 + lane] = v;
    if (lane == 0) { mA[ix] = m; nA[ix] = n; gA[ix] = g; }
  }
}

// ---- scan-apply: head-prefix aggregates + local scan -> linb, wtb, gcb ----
__global__ void scan_apply_k(const float* __restrict__ sim,
                             const float* __restrict__ mloc, const float* __restrict__ nloc,
                             const float* __restrict__ gloc, const float* __restrict__ vloc,
                             const float* __restrict__ mA, const float* __restrict__ nA,
                             const float* __restrict__ gA, const float* __restrict__ vA,
                             float* __restrict__ linb, float* __restrict__ wtb,
                             float* __restrict__ gcb) {
  int c = blockIdx.x, h = blockIdx.y;
  int tid = threadIdx.x, lane = tid & 63, w = tid >> 6;
  float m = -1e30f, n = 0.f, v = 0.f, g = 0.f;
  for (int cc = 0; cc < c; cc++) {
    size_t ix = (size_t)h * 16 + cc;
    float mb = mA[ix], nb = nA[ix], gb = gA[ix];
    float vb = vA[ix * 64 + lane];
    float mn = fmaxf(m, mb);
    float ea = expf(m - mn), eb = expf(mb - mn);
    n = n * ea + nb * eb;
    v = v * ea + vb * eb;
    m = mn; g += gb;
  }
#pragma unroll 4
  for (int i = 0; i < 16; i++) {
    int row = w * 16 + i;
    int gw = h * 1024 + c * 64 + row;
    float ml = mloc[gw], nl = nloc[gw], gl = gloc[gw];
    float vl = vloc[(size_t)gw * 64 + lane];
    float mf = fmaxf(m, ml);
    float ep = expf(m - mf), el = expf(ml - mf);
    float nf = n * ep + nl * el;
    float vf = v * ep + vl * el;
    float inv = 1.f / (nf + 1e-5f);
    linb[(size_t)gw * 64 + lane] = vf * inv;
    if (lane == 0) {
      wtb[gw] = expf(sim[gw] - mf) * inv;
      gcb[gw] = g + gl;
    }
  }
}

// ---- attn matmuls via MFMA + in-kernel Mc prefix: Y = q S + mask(q v^T)gz k
__launch_bounds__(256)
__global__ void attn_mm_k(const float* __restrict__ qkvf, const float* __restrict__ vn,
                          const float* __restrict__ kn, const float* __restrict__ gz,
                          const float* __restrict__ qs, const float* __restrict__ Mc,
                          const float* __restrict__ wtb, const float* __restrict__ gcb,
                          const float* __restrict__ linb, const float* __restrict__ scale,
                          const float* __restrict__ bias, float* __restrict__ Yc) {
  __shared__ bf16 qs_[64 * 72], vs_[64 * 72], ksT[64 * 72], SsT[64 * 72], Ps[64 * 72];
  __shared__ float gzs[64];
  int c = blockIdx.x, h = blockIdx.y, tid = threadIdx.x;
  int lane = tid & 63, w = tid >> 6;
  size_t base = ((size_t)h * 1024 + c * 64) * 64;
#pragma unroll
  for (int i = 0; i < 16; i++) {
    int e = i * 256 + tid, r = e >> 6, cc = e & 63;
    float qv = qkvf[(size_t)(c * 64 + r) * 1024 + h * 64 + cc]
             + qkvf[(size_t)(c * 64 + r) * 1024 + h * 64 + cc + 3145728]
             + bias[h * 64 + cc];
    qs_[r * 72 + cc] = __float2bfloat16(qv);
    vs_[r * 72 + cc] = __float2bfloat16(vn[base + e]);
    ksT[cc * 72 + r] = __float2bfloat16(kn[base + e]);
  }
  if (tid < 64) gzs[tid] = gz[h * 1024 + c * 64 + tid];
  // exclusive Mc prefix over chunks < c -> SsT (transposed bf16)
  {
    float4 a0 = {0,0,0,0}, a1 = {0,0,0,0}, a2 = {0,0,0,0}, a3 = {0,0,0,0};
    const float* McH = Mc + (size_t)h * 16 * 4096;
    for (int cc = 0; cc < c; cc++) {
      const float4* p = (const float4*)(McH + cc * 4096) + tid * 4;
      float4 t0 = p[0], t1 = p[1], t2 = p[2], t3 = p[3];
      a0.x += t0.x; a0.y += t0.y; a0.z += t0.z; a0.w += t0.w;
      a1.x += t1.x; a1.y += t1.y; a1.z += t1.z; a1.w += t1.w;
      a2.x += t2.x; a2.y += t2.y; a2.z += t2.z; a2.w += t2.w;
      a3.x += t3.x; a3.y += t3.y; a3.z += t3.z; a3.w += t3.w;
    }
    float4 av[4] = {a0, a1, a2, a3};
#pragma unroll
    for (int j = 0; j < 4; j++) {
      int idx = tid * 4 + j;
      int p = idx >> 4, nb = (idx & 15) * 4;
      SsT[(nb + 0) * 72 + p] = __float2bfloat16(av[j].x);
      SsT[(nb + 1) * 72 + p] = __float2bfloat16(av[j].y);
      SsT[(nb + 2) * 72 + p] = __float2bfloat16(av[j].z);
      SsT[(nb + 3) * 72 + p] = __float2bfloat16(av[j].w);
    }
  }
  __syncthreads();
  const int fr = lane & 15, fq = lane >> 4;
  const int colo0 = fq * 8;
  // P = mask(q . v^T) * gz   (wave w owns t rows w*16..w*16+15)
  {
    f32x4 pacc[4] = {};
#pragma unroll
    for (int ks2 = 0; ks2 < 2; ks2++) {
      int colo = ks2 * 32 + colo0;
      short8 a = *(const short8*)&qs_[(w * 16 + fr) * 72 + colo];
#pragma unroll
      for (int st = 0; st < 4; st++) {
        short8 b = *(const short8*)&vs_[(st * 16 + fr) * 72 + colo];
        pacc[st] = __builtin_amdgcn_mfma_f32_16x16x32_bf16(a, b, pacc[st], 0, 0, 0);
      }
    }
#pragma unroll
    for (int st = 0; st < 4; st++) {
      int s = st * 16 + fr;
      float g = gzs[s];
#pragma unroll
      for (int j = 0; j < 4; j++) {
        int t = w * 16 + fq * 4 + j;
        Ps[t * 72 + s] = __float2bfloat16((s <= t) ? pacc[st][j] * g : 0.f);
      }
    }
  }
  __syncthreads();
  // Y = q.S + P.k
  f32x4 y[4] = {};
#pragma unroll
  for (int ks2 = 0; ks2 < 2; ks2++) {
    int colo = ks2 * 32 + colo0;
    short8 a  = *(const short8*)&qs_[(w * 16 + fr) * 72 + colo];
    short8 a2 = *(const short8*)&Ps[(w * 16 + fr) * 72 + colo];
#pragma unroll
    for (int nt = 0; nt < 4; nt++) {
      short8 b  = *(const short8*)&SsT[(nt * 16 + fr) * 72 + colo];
      short8 b2 = *(const short8*)&ksT[(nt * 16 + fr) * 72 + colo];
      y[nt] = __builtin_amdgcn_mfma_f32_16x16x32_bf16(a, b, y[nt], 0, 0, 0);
      y[nt] = __builtin_amdgcn_mfma_f32_16x16x32_bf16(a2, b2, y[nt], 0, 0, 0);
    }
  }
  // epilogue + blend
  float sc = scale[h];
#pragma unroll
  for (int j = 0; j < 4; j++) {
    int t = w * 16 + fq * 4 + j;
    int l = c * 64 + t;
    size_t il = (size_t)h * 1024 + l;
    float gcv = gcb[il], wv = wtb[il], qv = qs[il];
    float den = 1.f / (gcv + 1e-5f);
#pragma unroll
    for (int nt = 0; nt < 4; nt++) {
      int n = nt * 16 + fr;
      float yb = sc * y[nt][j] * den;
      float yl = qv * linb[il * 64 + n];
      Yc[(size_t)l * 1024 + h * 64 + n] = yb + (yl - yb) * wv;
    }
  }
}

// ---------------- row l2norm over D=1024 + cast ----------------
__global__ void rownorm_cast_k(const float* __restrict__ Y, bf16* __restrict__ out) {
  __shared__ float red[4];
  int l = blockIdx.x, tid = threadIdx.x;
  float4 v = ((const float4*)(Y + (size_t)l * 1024))[tid];
  float ss = v.x * v.x + v.y * v.y + v.z * v.z + v.w * v.w;
  ss = wave_sum(ss);
  int wid = tid >> 6, lane = tid & 63;
  if (lane == 0) red[wid] = ss;
  __syncthreads();
  float tot = red[0] + red[1] + red[2] + red[3];
  float inv = 1.f / fmaxf(sqrtf(tot), 1e-12f);
  bf16x4 o;
  o.v[0] = __float2bfloat16(v.x * inv); o.v[1] = __float2bfloat16(v.y * inv);
  o.v[2] = __float2bfloat16(v.z * inv); o.v[3] = __float2bfloat16(v.w * inv);
  ((bf16x4*)(out + (size_t)l * 1024))[tid] = o;
}

// ======================================================================
extern "C" void kernel_launch(void* const* d_in, const int* in_sizes, int n_in,
                              void* d_out, int out_size, void* d_ws, size_t ws_size,
                              hipStream_t stream) {
  (void)in_sizes; (void)n_in; (void)out_size; (void)ws_size;
  const float* x     = (const float*)d_in[0];
  const float* basis = (const float*)d_in[1];
  const float* mphiW = (const float*)d_in[2];
  const float* mphiB = (const float*)d_in[3];
  const float* wqW = (const float*)d_in[4];  const float* wqB = (const float*)d_in[5];
  const float* wkW = (const float*)d_in[6];  const float* wkB = (const float*)d_in[7];
  const float* wvW = (const float*)d_in[8];  const float* wvB = (const float*)d_in[9];
  const float* woW = (const float*)d_in[10]; const float* woB = (const float*)d_in[11];
  const float* wgW = (const float*)d_in[12]; const float* wgB = (const float*)d_in[13];
  const float* kvs = (const float*)d_in[14];
  float* out = (float*)d_out;
  char* ws = (char*)d_ws;

  bf16*  Y_T     = (bf16*)(ws + 0x0000000UL);   // [16][1024 o][1024 s] bf16 (32MB)
  bf16*  Tbuf    = (bf16*)(ws + 0x2000000UL);   // [16][1024 l][1024 s] bf16 (32MB)
  float* part2a  = (float*)(ws + 0x4000000UL);  // [8][1M] f32 (32MB)
  float* qkvf    = (float*)(ws + 0x4000000UL);  // [6][1M] f32 (24MB, after reduce16)
  float* part8   = (float*)(ws + 0x4000000UL);  // [4][1M] f32 (after attn_mm)
  bf16*  x_bf    = (bf16*)(ws + 0x6000000UL);   // (2MB)
  bf16*  xtil_bf = (bf16*)(ws + 0x6200000UL);   // (2MB)
  bf16*  wqkv_bf = (bf16*)(ws + 0x6400000UL);   // (6MB)
  bf16*  wo_bf   = (bf16*)(ws + 0x6A00000UL);   // (2MB)
  float* qkv_bias= (float*)(ws + 0x6C00000UL);  // (64KB)
  float* part2b  = (float*)(ws + 0x6C10000UL);  // [8][1M] f32 (32MB; dead after reduce16)
  // post-reduce16 buffers (inside the dead part2b region):
  float* kn      = (float*)(ws + 0x6C10000UL);  // [16,1024,64] (4MB)
  float* vn      = (float*)(ws + 0x7010000UL);  // (4MB)
  float* Mc      = (float*)(ws + 0x7410000UL);  // [16][16][4096] (4MB)
  float* Yc      = (float*)(ws + 0x7810000UL);  // [1024][1024] f32 (4MB)
  bf16*  ynorm   = (bf16*)(ws + 0x7C10000UL);   // (2MB)
  float* simb    = (float*)(ws + 0x7E10000UL);
  float* gzb     = (float*)(ws + 0x7E20000UL);
  float* qsb     = (float*)(ws + 0x7E30000UL);
  float* wtb     = (float*)(ws + 0x7E40000UL);
  float* gcb     = (float*)(ws + 0x7E50000UL);
  // scan scratch (inside dead Tbuf region, after stage-B):
  float* vloc = (float*)(ws + 0x2000000UL);  // [16,1024,64] (4MB)
  float* mloc = (float*)(ws + 0x2400000UL);
  float* nloc = (float*)(ws + 0x2410000UL);
  float* gloc = (float*)(ws + 0x2420000UL);
  float* mA   = (float*)(ws + 0x2430000UL);
  float* nA   = (float*)(ws + 0x2431000UL);
  float* gA   = (float*)(ws + 0x2432000UL);
  float* vA   = (float*)(ws + 0x2440000UL);  // [16,16,64]
  float* linb = (float*)(ws + 0x2500000UL);  // [16,1024,64] (4MB)

  // prep: build_T + small casts (mphiW cast fused into stage-A)
  prep_cast_k<<<10765, 256, 0, stream>>>(wqW, wkW, wvW, woW, x, wqB, wkB, wvB,
                                         basis, wqkv_bf, wo_bf, x_bf,
                                         qkv_bias, Tbuf);

  // stage-A: Y_T[k][o][s] = Mphi_k @ X^T  (fused f32->bf16 A-side cast)
  gemm_castA_k<<<1024, 256, 0, stream>>>(mphiW, x_bf, Y_T);

  // stage-B: x_tilde = sum_k T_k @ Y_T[k]^T  (triangular, split-K x16)
  gemm_bt<1, 0, 0, 0, 0><<<1024, 256, 0, stream>>>(
      Tbuf, 1048576L, 1024, Y_T, 1048576L, 1024, (void*)part2a, (void*)part2b, 8,
      1048576L, 1024, nullptr, 0, 1024);
  reduce16_k<<<1024, 256, 0, stream>>>(part2a, part2b, mphiB, xtil_bf);

  // stage3: q,k,v (split-K x2, 6 z-slabs; bias folded into consumers)
  gemm_bt<0, 0, 0, 1, 1><<<384, 256, 0, stream>>>(
      xtil_bf, 0L, 1024, wqkv_bf, 1048576L, 1024, (void*)qkvf, (void*)qkvf, 1 << 28,
      1048576L, 1024, nullptr, 0, 512);

  // stage4: sum halves + bias; normalize k,v; sim; qsum; gates
  qkv_post_k<<<4096, 256, 0, stream>>>(qkvf, wgW, wgB, kvs, qkv_bias,
                                       kn, vn, simb, gzb, qsb);

  // stage5+6a: fused local scan + gated outer product
  scan_outer_k<<<dim3(16, 16), 256, 0, stream>>>(simb, gzb, vn, kn,
                                                 vloc, mloc, nloc, gloc,
                                                 mA, nA, vA, gA, Mc);

  // stage6b: scan-apply (-> linb, wtb, gcb)
  scan_apply_k<<<dim3(16, 16), 256, 0, stream>>>(simb, mloc, nloc, gloc, vloc,
                                                 mA, nA, gA, vA, linb, wtb, gcb);

  // stage6c: attn matmuls via MFMA (in-kernel Mc prefix) + blend
  attn_mm_k<<<dim3(16, 16), 256, 0, stream>>>(qkvf, vn, kn, gzb, qsb, Mc,
                                              wtb, gcb, linb, kvs, qkv_bias, Yc);

  // stage7: row l2norm + cast
  rownorm_cast_k<<<1024, 256, 0, stream>>>(Yc, ynorm);

  // stage8: out = Ynorm @ wo^T + b (split-K x4)
  gemm_bt<0, 0, 0, 1, 0><<<256, 256, 0, stream>>>(
      ynorm, 256L, 1024, wo_bf, 256L, 1024, (void*)part8, (void*)part8, 1 << 28,
      1048576L, 1024, nullptr, 0, 256);
  reduce4f_k<<<1024, 256, 0, stream>>>(part8, woB, out);
}

// Round 21
// 233.011 us; speedup vs baseline: 1.0201x; 1.0201x over previous
//
#include <hip/hip_runtime.h>
#include <hip/hip_bf16.h>

typedef __hip_bfloat16 bf16;
typedef __attribute__((ext_vector_type(8))) short short8;
typedef __attribute__((ext_vector_type(4))) float f32x4;

struct bf16x8 { bf16 v[8]; };
struct bf16x4 { bf16 v[4]; };

__device__ __forceinline__ void gload_lds16(const void* g, void* l) {
  __builtin_amdgcn_global_load_lds(
      (const __attribute__((address_space(1))) void*)g,
      (__attribute__((address_space(3))) void*)l, 16, 0, 0);
}

__device__ __forceinline__ float wave_sum(float x) {
#pragma unroll
  for (int o = 32; o > 0; o >>= 1) x += __shfl_xor(x, o, 64);
  return x;
}

// ---- fused prep: build T first, then cast mphiW + wq/wk/wv/wo + x + bias --
__global__ void prep_cast_k(const float* __restrict__ mphiW,
                            const float* __restrict__ wq, const float* __restrict__ wk,
                            const float* __restrict__ wv, const float* __restrict__ wo,
                            const float* __restrict__ x,
                            const float* __restrict__ bq, const float* __restrict__ bk,
                            const float* __restrict__ bv,
                            const float* __restrict__ basis,
                            bf16* __restrict__ mphi_bf, bf16* __restrict__ wqkv,
                            bf16* __restrict__ wo_bf, bf16* __restrict__ x_bf,
                            float* __restrict__ qkv_bias, bf16* __restrict__ T) {
  int b = blockIdx.x, tid = threadIdx.x;
  if (b < 8192) {  // build T[k][l][s]
    size_t i8 = (size_t)b * 256 + tid;  // 2M
    size_t i = i8 * 8;
    int s0 = (int)(i & 1023);
    int l = (int)((i >> 10) & 1023);
    int k = (int)(i >> 20);
    bf16x8 o;
#pragma unroll
    for (int j = 0; j < 8; j++) {
      int s = s0 + j;
      o.v[j] = (s <= l) ? __float2bfloat16(basis[(size_t)(l - s) * 16 + k])
                        : __float2bfloat16(0.f);
    }
    ((bf16x8*)T)[i8] = o;
    return;
  }
  const float* src; bf16* dst; int i;
  if (b < 16384) { src = mphiW; dst = mphi_bf; i = (b - 8192) * 256 + tid; }
  else if (b < 18432) {
    int bb = b - 16384;
    src = (bb < 512) ? wq : (bb < 1024) ? wk : (bb < 1536) ? wv : wo;
    dst = (bb < 512) ? wqkv : (bb < 1024) ? (wqkv + 1048576)
         : (bb < 1536) ? (wqkv + 2097152) : wo_bf;
    i = (bb & 511) * 256 + tid;
  } else if (b < 18944) { src = x; dst = x_bf; i = (b - 18432) * 256 + tid; }
  else {
    int j = (b - 18944) * 256 + tid;
    if (j < 3072) {
      const float* s = (j < 1024) ? bq : (j < 2048) ? bk : bv;
      qkv_bias[j] = s[j & 1023];
    }
    return;
  }
  const float4* p = (const float4*)src + (size_t)i * 2;
  float4 a = p[0], c = p[1];
  bf16x8 o;
  o.v[0] = __float2bfloat16(a.x); o.v[1] = __float2bfloat16(a.y);
  o.v[2] = __float2bfloat16(a.z); o.v[3] = __float2bfloat16(a.w);
  o.v[4] = __float2bfloat16(c.x); o.v[5] = __float2bfloat16(c.y);
  o.v[6] = __float2bfloat16(c.z); o.v[7] = __float2bfloat16(c.w);
  ((bf16x8*)dst)[i] = o;
}

// ---------------- MFMA GEMM, C = A @ B^T (+bias). 128x128 tile, BK=64 ------
// SK3=1: stage3 mode, bz in [0,6) = (khalf*3 + w); A off = khalf*512,
// B off = w*sBb + khalf*512, C slab = bz.
template<int TRI, int OUTBF, int HASB, int DBUF, int SK3>
__global__ void gemm_bt(const bf16* __restrict__ A, long sAb, int lda,
                        const bf16* __restrict__ B, long sBb, int ldb,
                        void* __restrict__ Cv, void* __restrict__ Cv2, int nbz1,
                        long sCb, int ldc,
                        const float* __restrict__ bias, int sbias, int K) {
  constexpr int NB = DBUF ? 2 : 1;
  __shared__ bf16 As[NB][128 * 64];
  __shared__ bf16 Bs[NB][128 * 64];
  const int tid = threadIdx.x;
  const int lane = tid & 63;
  const int wid = tid >> 6;
  const int wr = wid >> 1, wc = wid & 1;
  const int cpx = gridDim.x >> 3;
  const int logical = (blockIdx.x & 7) * cpx + (blockIdx.x >> 3);
  const int bx = logical & 7, by = (logical >> 3) & 7, bz = logical >> 6;
  const int r0 = by * 128, c0 = bx * 128;
  const bf16* Ab;
  const bf16* Bb;
  if (SK3) {
    int w_ = bz % 3, kh_ = bz / 3;
    Ab = A + kh_ * 512;
    Bb = B + (size_t)w_ * sBb + kh_ * 512;
  } else {
    Ab = A + (size_t)bz * sAb;
    Bb = B + (size_t)bz * sBb;
  }
  f32x4 acc[4][4] = {};
  const int nt = (TRI ? min(K, r0 + 128) : K) >> 6;

  const int srow = tid >> 3, scol = (tid & 7) << 3;

#define STAGE(buf, t)                                                         \
  {                                                                           \
    const int k0_ = (t) << 6;                                                 \
    _Pragma("unroll")                                                         \
    for (int i = 0; i < 4; i++) {                                             \
      int row = i * 32 + srow;                                                \
      gload_lds16(Ab + (size_t)(r0 + row) * lda + k0_ + scol,                 \
                  &As[buf][(row << 6) + scol]);                               \
    }                                                                         \
    _Pragma("unroll")                                                         \
    for (int i = 0; i < 4; i++) {                                             \
      int row = i * 32 + srow;                                                \
      gload_lds16(Bb + (size_t)(c0 + row) * ldb + k0_ + scol,                 \
                  &Bs[buf][(row << 6) + scol]);                               \
    }                                                                         \
  }

  int cur = 0;
  if (DBUF) STAGE(0, 0)
  for (int t = 0; t < nt; ++t) {
    if (DBUF) {
      if (t + 1 < nt) {
        STAGE(cur ^ 1, t + 1)
        asm volatile("s_waitcnt vmcnt(8)" ::: "memory");
      } else {
        asm volatile("s_waitcnt vmcnt(0)" ::: "memory");
      }
      __syncthreads();
    } else {
      __syncthreads();
      STAGE(0, t)
      asm volatile("s_waitcnt vmcnt(0)" ::: "memory");
      __syncthreads();
    }
#pragma unroll
    for (int ks = 0; ks < 2; ks++) {
      const int colo = ks * 32 + (lane >> 4) * 8;
      short8 af[4], bfr[4];
#pragma unroll
      for (int m = 0; m < 4; m++)
        af[m] = *(const short8*)&As[cur][(wr * 64 + m * 16 + (lane & 15)) * 64 + colo];
#pragma unroll
      for (int n = 0; n < 4; n++)
        bfr[n] = *(const short8*)&Bs[cur][(wc * 64 + n * 16 + (lane & 15)) * 64 + colo];
#pragma unroll
      for (int m = 0; m < 4; m++)
#pragma unroll
        for (int n = 0; n < 4; n++)
          acc[m][n] = __builtin_amdgcn_mfma_f32_16x16x32_bf16(af[m], bfr[n], acc[m][n], 0, 0, 0);
    }
    if (DBUF) { __syncthreads(); cur ^= 1; }
  }
#undef STAGE

  void* Cb = (bz < nbz1) ? Cv : Cv2;
  const int bzl = (bz < nbz1) ? bz : bz - nbz1;
  const int rb = r0 + wr * 64 + ((lane >> 4) << 2);
  const int cb = c0 + wc * 64 + (lane & 15);
#pragma unroll
  for (int n = 0; n < 4; n++) {
    const int col = cb + n * 16;
    float bv = HASB ? bias[bz * sbias + col] : 0.f;
#pragma unroll
    for (int m = 0; m < 4; m++) {
#pragma unroll
      for (int j = 0; j < 4; j++) {
        const int row = rb + m * 16 + j;
        size_t off = (size_t)bzl * sCb + (size_t)row * ldc + col;
        float v = acc[m][n][j] + bv;
        if (OUTBF) ((bf16*)Cb)[off] = __float2bfloat16(v);
        else       ((float*)Cb)[off] = v;
      }
    }
  }
}

// ---------------- split-K x16 reduce (two regions) + bias + cast -----------
__global__ void reduce16_k(const float* __restrict__ pA, const float* __restrict__ pB,
                           const float* __restrict__ bias, bf16* __restrict__ out) {
  int i4 = blockIdx.x * 256 + threadIdx.x;  // 256K float4s
  float4 v = *((const float4*)bias + (i4 & 255));
#pragma unroll
  for (int j = 0; j < 8; j++) {
    float4 a = *((const float4*)pA + i4 + j * 262144);
    v.x += a.x; v.y += a.y; v.z += a.z; v.w += a.w;
  }
#pragma unroll
  for (int j = 0; j < 8; j++) {
    float4 a = *((const float4*)pB + i4 + j * 262144);
    v.x += a.x; v.y += a.y; v.z += a.z; v.w += a.w;
  }
  bf16x4 o;
  o.v[0] = __float2bfloat16(v.x); o.v[1] = __float2bfloat16(v.y);
  o.v[2] = __float2bfloat16(v.z); o.v[3] = __float2bfloat16(v.w);
  ((bf16x4*)out)[i4] = o;
}

// ---------------- split-K x4 reduce + bias, f32 out ----------------
__global__ void reduce4f_k(const float* __restrict__ p, const float* __restrict__ bias,
                           float* __restrict__ out) {
  int i4 = blockIdx.x * 256 + threadIdx.x;  // 256K float4s
  float4 v = *((const float4*)bias + (i4 & 255));
#pragma unroll
  for (int j = 0; j < 4; j++) {
    float4 a = *((const float4*)p + i4 + j * 262144);
    v.x += a.x; v.y += a.y; v.z += a.z; v.w += a.w;
  }
  ((float4*)out)[i4] = v;
}

// ---- per-(h,l): sum split-K halves + bias; l2norm k,v; sim; qsum; gate ----
__global__ void qkv_post_k(const float* __restrict__ qkv, const float* __restrict__ W,
                           const float* __restrict__ wgb, const float* __restrict__ scale,
                           const float* __restrict__ bias,
                           float* __restrict__ kn, float* __restrict__ vn,
                           float* __restrict__ sim, float* __restrict__ gz, float* __restrict__ qs) {
  __shared__ float Wl[64][65];
  int tid = threadIdx.x;
#pragma unroll
  for (int i = 0; i < 16; i++) {
    int c = i * 256 + tid;
    Wl[c >> 6][c & 63] = W[c];
  }
  __syncthreads();
  int lane = tid & 63;
  int gw = blockIdx.x * 4 + (tid >> 6);
  int h = gw >> 10, l = gw & 1023;
  const float* base = qkv + (size_t)l * 1024 + h * 64 + lane;
  float q = base[0] + base[3145728] + bias[h * 64 + lane];
  float k = base[1048576] + base[4194304] + bias[1024 + h * 64 + lane];
  float v = base[2097152] + base[5242880] + bias[2048 + h * 64 + lane];
  float knv = k * (1.f / fmaxf(sqrtf(wave_sum(k * k)), 1e-12f));
  float vnv = v * (1.f / fmaxf(sqrtf(wave_sum(v * v)), 1e-12f));
  float simv = wave_sum(q * knv);
  float qsv = wave_sum(q);
  float inner = 0.f;
#pragma unroll 8
  for (int n = 0; n < 64; n++)
    inner += Wl[lane][n] * __shfl(knv, n, 64);
  float gl = wave_sum(vnv * inner) * scale[h] + wgb[0];
  float yy = gl > 0.f ? gl : 0.01f * gl;
  float gzz = yy * yy + 1e-5f;
  size_t o = ((size_t)h * 1024 + l) * 64 + lane;
  kn[o] = knv; vn[o] = vnv;
  if (lane == 0) {
    sim[h * 1024 + l] = simv; gz[h * 1024 + l] = gzz; qs[h * 1024 + l] = qsv;
  }
}

// ---- fused: per-(c,h) local softmax-scan + gated outer-product state ------
__global__ void scan_outer_k(const float* __restrict__ sim, const float* __restrict__ gz,
                             const float* __restrict__ vn, const float* __restrict__ kn,
                             float* __restrict__ vloc, float* __restrict__ mloc,
                             float* __restrict__ nloc, float* __restrict__ gloc,
                             float* __restrict__ mA, float* __restrict__ nA,
                             float* __restrict__ vA, float* __restrict__ gA,
                             float* __restrict__ Mc) {
  __shared__ float vns[64][64], kns[64][64], gzs[64];
  int c = blockIdx.x, h = blockIdx.y, tid = threadIdx.x;
  size_t base = ((size_t)h * 1024 + c * 64) * 64;
#pragma unroll
  for (int i = 0; i < 16; i++) {
    int e = i * 256 + tid;
    vns[e >> 6][e & 63] = vn[base + e];
    kns[e >> 6][e & 63] = kn[base + e];
  }
  if (tid < 64) gzs[tid] = gz[h * 1024 + c * 64 + tid];
  __syncthreads();
  float acc[16] = {};
  for (int s = 0; s < 64; s++) {
    float g = gzs[s];
#pragma unroll
    for (int i = 0; i < 16; i++) {
      int pn = i * 256 + tid;
      acc[i] += (g * vns[s][pn >> 6]) * kns[s][pn & 63];
    }
  }
  size_t ob = (size_t)(h * 16 + c) * 4096;
#pragma unroll
  for (int i = 0; i < 16; i++) Mc[ob + i * 256 + tid] = acc[i];
  if (tid < 64) {
    int lane = tid;
    size_t hb = (size_t)h * 1024 + c * 64;
    float m = -1e30f, n = 0.f, v = 0.f, g = 0.f;
    for (int i = 0; i < 64; i++) {
      float s = sim[hb + i];
      float vv = vns[i][lane];
      float mn = fmaxf(m, s);
      float eo = expf(m - mn);
      float en = expf(s - mn);
      n = n * eo + en;
      v = v * eo + en * vv;
      m = mn;
      g += gzs[i];
      vloc[(hb + i) * 64 + lane] = v;
      if (lane == 0) { mloc[hb + i] = m; nloc[hb + i] = n; gloc[hb + i] = g; }
    }
    size_t ix = (size_t)h * 16 + c;
    vA[ix * 64 + lane] = v;
    if (lane == 0) { mA[ix] = m; nA[ix] = n; gA[ix] = g; }
  }
}

// ---- scan-apply: head-prefix aggregates + local scan -> linb, wtb, gcb ----
__global__ void scan_apply_k(const float* __restrict__ sim,
                             const float* __restrict__ mloc, const float* __restrict__ nloc,
                             const float* __restrict__ gloc, const float* __restrict__ vloc,
                             const float* __restrict__ mA, const float* __restrict__ nA,
                             const float* __restrict__ gA, const float* __restrict__ vA,
                             float* __restrict__ linb, float* __restrict__ wtb,
                             float* __restrict__ gcb) {
  int c = blockIdx.x, h = blockIdx.y;
  int tid = threadIdx.x, lane = tid & 63, w = tid >> 6;
  float m = -1e30f, n = 0.f, v = 0.f, g = 0.f;
  for (int cc = 0; cc < c; cc++) {
    size_t ix = (size_t)h * 16 + cc;
    float mb = mA[ix], nb = nA[ix], gb = gA[ix];
    float vb = vA[ix * 64 + lane];
    float mn = fmaxf(m, mb);
    float ea = expf(m - mn), eb = expf(mb - mn);
    n = n * ea + nb * eb;
    v = v * ea + vb * eb;
    m = mn; g += gb;
  }
#pragma unroll 4
  for (int i = 0; i < 16; i++) {
    int row = w * 16 + i;
    int gw = h * 1024 + c * 64 + row;
    float ml = mloc[gw], nl = nloc[gw], gl = gloc[gw];
    float vl = vloc[(size_t)gw * 64 + lane];
    float mf = fmaxf(m, ml);
    float ep = expf(m - mf), el = expf(ml - mf);
    float nf = n * ep + nl * el;
    float vf = v * ep + vl * el;
    float inv = 1.f / (nf + 1e-5f);
    linb[(size_t)gw * 64 + lane] = vf * inv;
    if (lane == 0) {
      wtb[gw] = expf(sim[gw] - mf) * inv;
      gcb[gw] = g + gl;
    }
  }
}

// ---- attn matmuls via MFMA + in-kernel Mc prefix: Y = q S + mask(q v^T)gz k
__launch_bounds__(256)
__global__ void attn_mm_k(const float* __restrict__ qkvf, const float* __restrict__ vn,
                          const float* __restrict__ kn, const float* __restrict__ gz,
                          const float* __restrict__ qs, const float* __restrict__ Mc,
                          const float* __restrict__ wtb, const float* __restrict__ gcb,
                          const float* __restrict__ linb, const float* __restrict__ scale,
                          const float* __restrict__ bias, float* __restrict__ Yc) {
  __shared__ bf16 qs_[64 * 72], vs_[64 * 72], ksT[64 * 72], SsT[64 * 72], Ps[64 * 72];
  __shared__ float gzs[64];
  int c = blockIdx.x, h = blockIdx.y, tid = threadIdx.x;
  int lane = tid & 63, w = tid >> 6;
  size_t base = ((size_t)h * 1024 + c * 64) * 64;
#pragma unroll
  for (int i = 0; i < 16; i++) {
    int e = i * 256 + tid, r = e >> 6, cc = e & 63;
    float qv = qkvf[(size_t)(c * 64 + r) * 1024 + h * 64 + cc]
             + qkvf[(size_t)(c * 64 + r) * 1024 + h * 64 + cc + 3145728]
             + bias[h * 64 + cc];
    qs_[r * 72 + cc] = __float2bfloat16(qv);
    vs_[r * 72 + cc] = __float2bfloat16(vn[base + e]);
    ksT[cc * 72 + r] = __float2bfloat16(kn[base + e]);
  }
  if (tid < 64) gzs[tid] = gz[h * 1024 + c * 64 + tid];
  // exclusive Mc prefix over chunks < c -> SsT (transposed bf16)
  {
    float4 a0 = {0,0,0,0}, a1 = {0,0,0,0}, a2 = {0,0,0,0}, a3 = {0,0,0,0};
    const float* McH = Mc + (size_t)h * 16 * 4096;
    for (int cc = 0; cc < c; cc++) {
      const float4* p = (const float4*)(McH + cc * 4096) + tid * 4;
      float4 t0 = p[0], t1 = p[1], t2 = p[2], t3 = p[3];
      a0.x += t0.x; a0.y += t0.y; a0.z += t0.z; a0.w += t0.w;
      a1.x += t1.x; a1.y += t1.y; a1.z += t1.z; a1.w += t1.w;
      a2.x += t2.x; a2.y += t2.y; a2.z += t2.z; a2.w += t2.w;
      a3.x += t3.x; a3.y += t3.y; a3.z += t3.z; a3.w += t3.w;
    }
    float4 av[4] = {a0, a1, a2, a3};
#pragma unroll
    for (int j = 0; j < 4; j++) {
      int idx = tid * 4 + j;
      int p = idx >> 4, nb = (idx & 15) * 4;
      SsT[(nb + 0) * 72 + p] = __float2bfloat16(av[j].x);
      SsT[(nb + 1) * 72 + p] = __float2bfloat16(av[j].y);
      SsT[(nb + 2) * 72 + p] = __float2bfloat16(av[j].z);
      SsT[(nb + 3) * 72 + p] = __float2bfloat16(av[j].w);
    }
  }
  __syncthreads();
  const int fr = lane & 15, fq = lane >> 4;
  const int colo0 = fq * 8;
  // P = mask(q . v^T) * gz   (wave w owns t rows w*16..w*16+15)
  {
    f32x4 pacc[4] = {};
#pragma unroll
    for (int ks2 = 0; ks2 < 2; ks2++) {
      int colo = ks2 * 32 + colo0;
      short8 a = *(const short8*)&qs_[(w * 16 + fr) * 72 + colo];
#pragma unroll
      for (int st = 0; st < 4; st++) {
        short8 b = *(const short8*)&vs_[(st * 16 + fr) * 72 + colo];
        pacc[st] = __builtin_amdgcn_mfma_f32_16x16x32_bf16(a, b, pacc[st], 0, 0, 0);
      }
    }
#pragma unroll
    for (int st = 0; st < 4; st++) {
      int s = st * 16 + fr;
      float g = gzs[s];
#pragma unroll
      for (int j = 0; j < 4; j++) {
        int t = w * 16 + fq * 4 + j;
        Ps[t * 72 + s] = __float2bfloat16((s <= t) ? pacc[st][j] * g : 0.f);
      }
    }
  }
  __syncthreads();
  // Y = q.S + P.k
  f32x4 y[4] = {};
#pragma unroll
  for (int ks2 = 0; ks2 < 2; ks2++) {
    int colo = ks2 * 32 + colo0;
    short8 a  = *(const short8*)&qs_[(w * 16 + fr) * 72 + colo];
    short8 a2 = *(const short8*)&Ps[(w * 16 + fr) * 72 + colo];
#pragma unroll
    for (int nt = 0; nt < 4; nt++) {
      short8 b  = *(const short8*)&SsT[(nt * 16 + fr) * 72 + colo];
      short8 b2 = *(const short8*)&ksT[(nt * 16 + fr) * 72 + colo];
      y[nt] = __builtin_amdgcn_mfma_f32_16x16x32_bf16(a, b, y[nt], 0, 0, 0);
      y[nt] = __builtin_amdgcn_mfma_f32_16x16x32_bf16(a2, b2, y[nt], 0, 0, 0);
    }
  }
  // epilogue + blend
  float sc = scale[h];
#pragma unroll
  for (int j = 0; j < 4; j++) {
    int t = w * 16 + fq * 4 + j;
    int l = c * 64 + t;
    size_t il = (size_t)h * 1024 + l;
    float gcv = gcb[il], wv = wtb[il], qv = qs[il];
    float den = 1.f / (gcv + 1e-5f);
#pragma unroll
    for (int nt = 0; nt < 4; nt++) {
      int n = nt * 16 + fr;
      float yb = sc * y[nt][j] * den;
      float yl = qv * linb[il * 64 + n];
      Yc[(size_t)l * 1024 + h * 64 + n] = yb + (yl - yb) * wv;
    }
  }
}

// ---------------- row l2norm over D=1024 + cast ----------------
__global__ void rownorm_cast_k(const float* __restrict__ Y, bf16* __restrict__ out) {
  __shared__ float red[4];
  int l = blockIdx.x, tid = threadIdx.x;
  float4 v = ((const float4*)(Y + (size_t)l * 1024))[tid];
  float ss = v.x * v.x + v.y * v.y + v.z * v.z + v.w * v.w;
  ss = wave_sum(ss);
  int wid = tid >> 6, lane = tid & 63;
  if (lane == 0) red[wid] = ss;
  __syncthreads();
  float tot = red[0] + red[1] + red[2] + red[3];
  float inv = 1.f / fmaxf(sqrtf(tot), 1e-12f);
  bf16x4 o;
  o.v[0] = __float2bfloat16(v.x * inv); o.v[1] = __float2bfloat16(v.y * inv);
  o.v[2] = __float2bfloat16(v.z * inv); o.v[3] = __float2bfloat16(v.w * inv);
  ((bf16x4*)(out + (size_t)l * 1024))[tid] = o;
}

// ======================================================================
extern "C" void kernel_launch(void* const* d_in, const int* in_sizes, int n_in,
                              void* d_out, int out_size, void* d_ws, size_t ws_size,
                              hipStream_t stream) {
  (void)in_sizes; (void)n_in; (void)out_size; (void)ws_size;
  const float* x     = (const float*)d_in[0];
  const float* basis = (const float*)d_in[1];
  const float* mphiW = (const float*)d_in[2];
  const float* mphiB = (const float*)d_in[3];
  const float* wqW = (const float*)d_in[4];  const float* wqB = (const float*)d_in[5];
  const float* wkW = (const float*)d_in[6];  const float* wkB = (const float*)d_in[7];
  const float* wvW = (const float*)d_in[8];  const float* wvB = (const float*)d_in[9];
  const float* woW = (const float*)d_in[10]; const float* woB = (const float*)d_in[11];
  const float* wgW = (const float*)d_in[12]; const float* wgB = (const float*)d_in[13];
  const float* kvs = (const float*)d_in[14];
  float* out = (float*)d_out;
  char* ws = (char*)d_ws;

  bf16*  Y_T     = (bf16*)(ws + 0x0000000UL);   // [16][1024 o][1024 s] bf16 (32MB)
  bf16*  Tbuf    = (bf16*)(ws + 0x2000000UL);   // [16][1024 l][1024 s] bf16 (32MB)
  bf16*  mphi_bf = (bf16*)(ws + 0x4000000UL);   // [1024][16384] bf16 (32MB)
  float* part2a  = (float*)(ws + 0x4000000UL);  // [8][1M] f32 (aliases mphi; dead after stage-A)
  float* qkvf    = (float*)(ws + 0x4000000UL);  // [6][1M] f32 (24MB, after reduce16)
  float* part8   = (float*)(ws + 0x4000000UL);  // [4][1M] f32 (after attn_mm)
  bf16*  x_bf    = (bf16*)(ws + 0x6000000UL);   // (2MB)
  bf16*  xtil_bf = (bf16*)(ws + 0x6200000UL);   // (2MB)
  bf16*  wqkv_bf = (bf16*)(ws + 0x6400000UL);   // (6MB)
  bf16*  wo_bf   = (bf16*)(ws + 0x6A00000UL);   // (2MB)
  float* qkv_bias= (float*)(ws + 0x6C00000UL);  // (64KB)
  float* part2b  = (float*)(ws + 0x6C10000UL);  // [8][1M] f32 (32MB; dead after reduce16)
  // post-reduce16 buffers (inside the dead part2b region):
  float* kn      = (float*)(ws + 0x6C10000UL);  // [16,1024,64] (4MB)
  float* vn      = (float*)(ws + 0x7010000UL);  // (4MB)
  float* Mc      = (float*)(ws + 0x7410000UL);  // [16][16][4096] (4MB)
  float* Yc      = (float*)(ws + 0x7810000UL);  // [1024][1024] f32 (4MB)
  bf16*  ynorm   = (bf16*)(ws + 0x7C10000UL);   // (2MB)
  float* simb    = (float*)(ws + 0x7E10000UL);
  float* gzb     = (float*)(ws + 0x7E20000UL);
  float* qsb     = (float*)(ws + 0x7E30000UL);
  float* wtb     = (float*)(ws + 0x7E40000UL);
  float* gcb     = (float*)(ws + 0x7E50000UL);
  // scan scratch (inside dead Tbuf region, after stage-B):
  float* vloc = (float*)(ws + 0x2000000UL);  // [16,1024,64] (4MB)
  float* mloc = (float*)(ws + 0x2400000UL);
  float* nloc = (float*)(ws + 0x2410000UL);
  float* gloc = (float*)(ws + 0x2420000UL);
  float* mA   = (float*)(ws + 0x2430000UL);
  float* nA   = (float*)(ws + 0x2431000UL);
  float* gA   = (float*)(ws + 0x2432000UL);
  float* vA   = (float*)(ws + 0x2440000UL);  // [16,16,64]
  float* linb = (float*)(ws + 0x2500000UL);  // [16,1024,64] (4MB)

  // prep: build_T first (overlaps gather latency with streaming casts)
  prep_cast_k<<<18956, 256, 0, stream>>>(mphiW, wqW, wkW, wvW, woW, x, wqB, wkB, wvB,
                                         basis, mphi_bf, wqkv_bf, wo_bf, x_bf,
                                         qkv_bias, Tbuf);

  // stage-A: Y_T[k][o][s] = Mphi_k @ X^T  (16 batched dense GEMMs, K=1024)
  gemm_bt<0, 1, 0, 0, 0><<<1024, 256, 0, stream>>>(
      mphi_bf, 1024L, 16384, x_bf, 0L, 1024, (void*)Y_T, (void*)Y_T, 1 << 28,
      1048576L, 1024, nullptr, 0, 1024);

  // stage-B: x_tilde = sum_k T_k @ Y_T[k]^T  (triangular, split-K x16)
  gemm_bt<1, 0, 0, 0, 0><<<1024, 256, 0, stream>>>(
      Tbuf, 1048576L, 1024, Y_T, 1048576L, 1024, (void*)part2a, (void*)part2b, 8,
      1048576L, 1024, nullptr, 0, 1024);
  reduce16_k<<<1024, 256, 0, stream>>>(part2a, part2b, mphiB, xtil_bf);

  // stage3: q,k,v (split-K x2, 6 z-slabs; bias folded into consumers)
  gemm_bt<0, 0, 0, 1, 1><<<384, 256, 0, stream>>>(
      xtil_bf, 0L, 1024, wqkv_bf, 1048576L, 1024, (void*)qkvf, (void*)qkvf, 1 << 28,
      1048576L, 1024, nullptr, 0, 512);

  // stage4: sum halves + bias; normalize k,v; sim; qsum; gates
  qkv_post_k<<<4096, 256, 0, stream>>>(qkvf, wgW, wgB, kvs, qkv_bias,
                                       kn, vn, simb, gzb, qsb);

  // stage5+6a: fused local scan + gated outer product
  scan_outer_k<<<dim3(16, 16), 256, 0, stream>>>(simb, gzb, vn, kn,
                                                 vloc, mloc, nloc, gloc,
                                                 mA, nA, vA, gA, Mc);

  // stage6b: scan-apply (-> linb, wtb, gcb)
  scan_apply_k<<<dim3(16, 16), 256, 0, stream>>>(simb, mloc, nloc, gloc, vloc,
                                                 mA, nA, gA, vA, linb, wtb, gcb);

  // stage6c: attn matmuls via MFMA (in-kernel Mc prefix) + blend
  attn_mm_k<<<dim3(16, 16), 256, 0, stream>>>(qkvf, vn, kn, gzb, qsb, Mc,
                                              wtb, gcb, linb, kvs, qkv_bias, Yc);

  // stage7: row l2norm + cast
  rownorm_cast_k<<<1024, 256, 0, stream>>>(Yc, ynorm);

  // stage8: out = Ynorm @ wo^T + b (split-K x4)
  gemm_bt<0, 0, 0, 1, 0><<<256, 256, 0, stream>>>(
      ynorm, 256L, 1024, wo_bf, 256L, 1024, (void*)part8, (void*)part8, 1 << 28,
      1048576L, 1024, nullptr, 0, 256);
  reduce4f_k<<<1024, 256, 0, stream>>>(part8, woB, out);
}